// Round 20
// baseline (413.322 us; speedup 1.0000x reference)
//
#include <hip/hip_runtime.h>
#include <math.h>

#define NEG 0.2f

__device__ __forceinline__ float leaky(float x){ return x >= 0.f ? x : NEG*x; }

__device__ __forceinline__ unsigned short f2b(float f){
    unsigned u = __float_as_uint(f);
    unsigned r = u + 0x7fffu + ((u >> 16) & 1u);
    return (unsigned short)(r >> 16);
}

// ---------------- fused: rank chunk FIRST (real edges only), then g1 -------
// NOTE: atomic pass floor ~132us (memory-side RMW cap ~25G/s; ILP/padding/
// scope/role-split all measured null). Rank-first ordering hides the GEMM.
__global__ __launch_bounds__(256) void rg1(const float* __restrict__ x,
        const float* __restrict__ W1, const float* __restrict__ a_src,
        const float* __restrict__ a_dst, unsigned short* __restrict__ h1b,
        float* __restrict__ s1, float* __restrict__ d1, int N,
        const int* __restrict__ ei, int* __restrict__ cnt,
        unsigned* __restrict__ rank32, int E)
{
    __shared__ float wsh[128][64];
    const int tid = threadIdx.x;
    // ---- rank chunk (all blocks, FIRST; real edges only) ----
    int i0 = (blockIdx.x*256 + tid)*4;
    if (i0 < E){
        unsigned pk;
        if (i0 + 3 < E){
            int4 d4 = *(const int4*)(ei + E + i0);
            unsigned r0 = (unsigned)atomicAdd(&cnt[d4.x], 1);
            unsigned r1 = (unsigned)atomicAdd(&cnt[d4.y], 1);
            unsigned r2 = (unsigned)atomicAdd(&cnt[d4.z], 1);
            unsigned r3 = (unsigned)atomicAdd(&cnt[d4.w], 1);
            pk = (r0 & 255u) | ((r1 & 255u) << 8) | ((r2 & 255u) << 16) | ((r3 & 255u) << 24);
        } else {
            pk = 0u;
            #pragma unroll
            for (int u = 0; u < 4; ++u){
                int i = i0 + u;
                if (i < E){
                    int dst = ei[E + i];
                    pk |= ((unsigned)atomicAdd(&cnt[dst], 1) & 255u) << (u*8);
                }
            }
        }
        rank32[i0 >> 2] = pk;
    }
    // ---- GEMM tile (blocks < gG1) ----
    const int gG1 = (N + 63) >> 6;
    if ((int)blockIdx.x >= gG1) return;
    const int rowbase = blockIdx.x * 64;
    #pragma unroll
    for (int i = 0; i < 8; ++i){
        int g = tid + i*256;
        ((float4*)&wsh[0][0])[g] = ((const float4*)W1)[g];
    }
    __syncthreads();
    const int tx = tid & 15, ty = tid >> 4;
    const int r0 = rowbase + ty*4;
    const float4* xr0 = (const float4*)(x + (size_t)min(r0+0, N-1)*128);
    const float4* xr1 = (const float4*)(x + (size_t)min(r0+1, N-1)*128);
    const float4* xr2 = (const float4*)(x + (size_t)min(r0+2, N-1)*128);
    const float4* xr3 = (const float4*)(x + (size_t)min(r0+3, N-1)*128);
    float acc[4][4];
    #pragma unroll
    for (int j=0;j<4;++j){
        #pragma unroll
        for (int c=0;c<4;++c) acc[j][c]=0.f;
    }
    #pragma unroll 4
    for (int k4 = 0; k4 < 32; ++k4){
        float4 xv[4], wv[4];
        xv[0] = xr0[k4]; xv[1] = xr1[k4]; xv[2] = xr2[k4]; xv[3] = xr3[k4];
        #pragma unroll
        for (int i=0;i<4;++i) wv[i] = *(const float4*)&wsh[k4*4+i][tx*4];
        #pragma unroll
        for (int j=0;j<4;++j){
            float x0=xv[j].x, x1=xv[j].y, x2=xv[j].z, x3=xv[j].w;
            acc[j][0]=fmaf(x0,wv[0].x,acc[j][0]); acc[j][1]=fmaf(x0,wv[0].y,acc[j][1]);
            acc[j][2]=fmaf(x0,wv[0].z,acc[j][2]); acc[j][3]=fmaf(x0,wv[0].w,acc[j][3]);
            acc[j][0]=fmaf(x1,wv[1].x,acc[j][0]); acc[j][1]=fmaf(x1,wv[1].y,acc[j][1]);
            acc[j][2]=fmaf(x1,wv[1].z,acc[j][2]); acc[j][3]=fmaf(x1,wv[1].w,acc[j][3]);
            acc[j][0]=fmaf(x2,wv[2].x,acc[j][0]); acc[j][1]=fmaf(x2,wv[2].y,acc[j][1]);
            acc[j][2]=fmaf(x2,wv[2].z,acc[j][2]); acc[j][3]=fmaf(x2,wv[2].w,acc[j][3]);
            acc[j][0]=fmaf(x3,wv[3].x,acc[j][0]); acc[j][1]=fmaf(x3,wv[3].y,acc[j][1]);
            acc[j][2]=fmaf(x3,wv[3].z,acc[j][2]); acc[j][3]=fmaf(x3,wv[3].w,acc[j][3]);
        }
    }
    const float4 asv = *(const float4*)&a_src[tx*4];
    const float4 adv = *(const float4*)&a_dst[tx*4];
    #pragma unroll
    for (int j=0;j<4;++j){
        int r = rowbase + ty*4 + j;
        float sv = acc[j][0]*asv.x + acc[j][1]*asv.y + acc[j][2]*asv.z + acc[j][3]*asv.w;
        float dv = acc[j][0]*adv.x + acc[j][1]*adv.y + acc[j][2]*adv.z + acc[j][3]*adv.w;
        #pragma unroll
        for (int dd=8; dd>0; dd>>=1){ sv += __shfl_xor(sv, dd, 16); dv += __shfl_xor(dv, dd, 16); }
        if (r < N){
            uint2 pk;
            pk.x = (unsigned)f2b(acc[j][0]) | ((unsigned)f2b(acc[j][1]) << 16);
            pk.y = (unsigned)f2b(acc[j][2]) | ((unsigned)f2b(acc[j][3]) << 16);
            *(uint2*)&h1b[(size_t)r*64 + tx*4] = pk;
            if (tx == 0){ s1[r] = sv; d1[r] = dv; }
        }
    }
}

__global__ void k_scan1(const int* __restrict__ cnt, int* __restrict__ bsum, int n){
    __shared__ int sh[256];
    int b = blockIdx.x, tid = threadIdx.x;
    int start = b*1024, s = 0;
    for (int i = tid; i < 1024; i += 256){ int idx = start+i; s += (idx<n)?cnt[idx]:0; }
    sh[tid]=s; __syncthreads();
    for (int d=128; d>0; d>>=1){ if (tid<d) sh[tid]+=sh[tid+d]; __syncthreads(); }
    if (tid==0) bsum[b]=sh[0];
}
// scan3: rowptr from cnt_real + 1 slot/node (trailing self-loop slot)
__global__ void k_scan3(const int* __restrict__ cnt, const int* __restrict__ bsum,
                        int* __restrict__ rowptr, int n){
    __shared__ int sh[256];
    __shared__ int basesh;
    int b = blockIdx.x, tid = threadIdx.x;
    int pb = 0;
    for (int i = tid; i < b; i += 256) pb += bsum[i];
    sh[tid] = pb; __syncthreads();
    for (int d=128; d>0; d>>=1){ if (tid<d) sh[tid]+=sh[tid+d]; __syncthreads(); }
    if (tid==0) basesh = sh[0] + b*1024;   // +1 slot per preceding node
    __syncthreads();
    int base = basesh;
    __syncthreads();
    int i0 = b*1024 + tid*4;
    int v[4]; int local=0;
    #pragma unroll
    for (int k=0;k<4;k++){ int idx=i0+k; v[k]=(idx<n)?(cnt[idx]+1):0; local+=v[k]; }
    sh[tid]=local; __syncthreads();
    for (int d=1; d<256; d<<=1){
        int t = (tid>=d)? sh[tid-d] : 0;
        __syncthreads();
        sh[tid] += t;
        __syncthreads();
    }
    int off = base + sh[tid] - local;
    #pragma unroll
    for (int k=0;k<4;k++){
        int idx = i0+k;
        if (idx < n){
            rowptr[idx]=off; off += v[k];
            if (idx==n-1) rowptr[n]=off;
        }
    }
}

// ---------------- score: {src, p1} int2; self-loop -> last slot of row -----
__global__ void k_score(const int* __restrict__ ei, const unsigned* __restrict__ rank32,
                        const int* __restrict__ rowptr,
                        const float* __restrict__ s, const float* __restrict__ d,
                        int2* __restrict__ csrp, int E, int ET){
    int i = blockIdx.x*256 + threadIdx.x;
    if (i >= ET) return;
    if (i < E){
        int src = ei[i];
        int dst = ei[E + i];
        int lr = (int)((rank32[i >> 2] >> ((i & 3)*8)) & 255u);
        float pv = expf(leaky(s[src] + d[dst]));
        csrp[rowptr[dst] + lr] = make_int2(src, __float_as_int(pv));
    } else {
        int nn = i - E;
        float pv = expf(leaky(s[nn] + d[nn]));
        csrp[rowptr[nn+1] - 1] = make_int2(nn, __float_as_int(pv));
    }
}

// ---------------- a1 fused with g2: aggregate layer 1 -> h2b, s2, d2 -------
// NOTE: no shfl-broadcast of loaded data (unsound on this target — r1/2/19).
// csrp[k] loads have loop-independent addresses; compiler pipelines them.
__global__ __launch_bounds__(256) void a1(const int* __restrict__ rowptr,
        const int2* __restrict__ csrp, const unsigned short* __restrict__ h1b,
        const float* __restrict__ b1, const float* __restrict__ W2,
        const float* __restrict__ as2, const float* __restrict__ ad2,
        unsigned short* __restrict__ h2b, float* __restrict__ s2,
        float* __restrict__ d2, int N)
{
    int wid = threadIdx.x>>6, lane = threadIdx.x&63;
    int es = lane >> 3, cg = lane & 7;
    float2 w2r[8];
    #pragma unroll
    for (int j = 0; j < 8; ++j)
        w2r[j] = *(const float2*)&W2[(cg*8 + j)*16 + es*2];
    const float2 asv = *(const float2*)&as2[es*2];
    const float2 adv = *(const float2*)&ad2[es*2];
    int n = blockIdx.x*4 + wid;
    if (n >= N) return;
    int base = rowptr[n], end = rowptr[n+1];
    float a0=0.f,a1v=0.f,a2v=0.f,a3=0.f,a4=0.f,a5=0.f,a6=0.f,a7=0.f;
    float z = 0.f;
    for (int k = base + es; k < end; k += 8){
        int2 cp = csrp[k];
        float pv = __int_as_float(cp.y);
        z += pv;
        uint4 hv = *(const uint4*)(h1b + (size_t)cp.x*64 + cg*8);
        a0 = fmaf(pv, __uint_as_float(hv.x << 16),          a0);
        a1v= fmaf(pv, __uint_as_float(hv.x & 0xffff0000u),  a1v);
        a2v= fmaf(pv, __uint_as_float(hv.y << 16),          a2v);
        a3 = fmaf(pv, __uint_as_float(hv.y & 0xffff0000u),  a3);
        a4 = fmaf(pv, __uint_as_float(hv.z << 16),          a4);
        a5 = fmaf(pv, __uint_as_float(hv.z & 0xffff0000u),  a5);
        a6 = fmaf(pv, __uint_as_float(hv.w << 16),          a6);
        a7 = fmaf(pv, __uint_as_float(hv.w & 0xffff0000u),  a7);
    }
    #pragma unroll
    for (int m = 8; m <= 32; m <<= 1){
        a0 += __shfl_xor(a0, m); a1v += __shfl_xor(a1v, m);
        a2v += __shfl_xor(a2v, m); a3 += __shfl_xor(a3, m);
        a4 += __shfl_xor(a4, m); a5 += __shfl_xor(a5, m);
        a6 += __shfl_xor(a6, m); a7 += __shfl_xor(a7, m);
        z  += __shfl_xor(z, m);
    }
    float zi = 1.f/(z + 1e-16f);
    const float4 b0 = *(const float4*)(b1 + cg*8);
    const float4 b4 = *(const float4*)(b1 + cg*8 + 4);
    float o[8];
    o[0]=fmaxf(a0*zi + b0.x, 0.f); o[1]=fmaxf(a1v*zi + b0.y, 0.f);
    o[2]=fmaxf(a2v*zi + b0.z, 0.f); o[3]=fmaxf(a3*zi + b0.w, 0.f);
    o[4]=fmaxf(a4*zi + b4.x, 0.f); o[5]=fmaxf(a5*zi + b4.y, 0.f);
    o[6]=fmaxf(a6*zi + b4.z, 0.f); o[7]=fmaxf(a7*zi + b4.w, 0.f);
    float pc0 = 0.f, pc1 = 0.f;
    #pragma unroll
    for (int j = 0; j < 8; ++j){
        pc0 = fmaf(o[j], w2r[j].x, pc0);
        pc1 = fmaf(o[j], w2r[j].y, pc1);
    }
    #pragma unroll
    for (int m = 1; m <= 4; m <<= 1){ pc0 += __shfl_xor(pc0, m); pc1 += __shfl_xor(pc1, m); }
    float sp = pc0*asv.x + pc1*asv.y;
    float dp = pc0*adv.x + pc1*adv.y;
    #pragma unroll
    for (int m = 8; m <= 32; m <<= 1){ sp += __shfl_xor(sp, m); dp += __shfl_xor(dp, m); }
    if (cg == 0){
        unsigned pk = (unsigned)f2b(pc0) | ((unsigned)f2b(pc1) << 16);
        *(unsigned*)&h2b[(size_t)n*16 + es*2] = pk;
        if (es == 0){ s2[n] = sp; d2[n] = dp; }
    }
}

// ---------------- a2: aggregate layer 2 (p2 inline, f32) + log_softmax -----
__global__ __launch_bounds__(256) void a2(const int* __restrict__ rowptr,
        const int2* __restrict__ csrp, const unsigned short* __restrict__ h2b,
        const float* __restrict__ s2, const float* __restrict__ d2,
        const float* __restrict__ b2, float* __restrict__ out, int N)
{
    int wid = threadIdx.x>>6, lane = threadIdx.x&63;
    int n = blockIdx.x*4 + wid;
    if (n >= N) return;
    int base = rowptr[n], end = rowptr[n+1];
    int es = lane >> 1, cg = lane & 1;
    float dn = d2[n];
    float a[8] = {0.f,0.f,0.f,0.f,0.f,0.f,0.f,0.f};
    float z = 0.f;
    for (int k = base + es; k < end; k += 32){
        int2 cp = csrp[k];
        float pv = expf(leaky(s2[cp.x] + dn));
        z += pv;
        uint4 hv = *(const uint4*)(h2b + (size_t)cp.x*16 + cg*8);
        a[0] = fmaf(pv, __uint_as_float(hv.x << 16),          a[0]);
        a[1] = fmaf(pv, __uint_as_float(hv.x & 0xffff0000u),  a[1]);
        a[2] = fmaf(pv, __uint_as_float(hv.y << 16),          a[2]);
        a[3] = fmaf(pv, __uint_as_float(hv.y & 0xffff0000u),  a[3]);
        a[4] = fmaf(pv, __uint_as_float(hv.z << 16),          a[4]);
        a[5] = fmaf(pv, __uint_as_float(hv.z & 0xffff0000u),  a[5]);
        a[6] = fmaf(pv, __uint_as_float(hv.w << 16),          a[6]);
        a[7] = fmaf(pv, __uint_as_float(hv.w & 0xffff0000u),  a[7]);
    }
    #pragma unroll
    for (int m = 2; m <= 32; m <<= 1){
        #pragma unroll
        for (int j = 0; j < 8; ++j) a[j] += __shfl_xor(a[j], m);
        z += __shfl_xor(z, m);
    }
    float zi = 1.f/(z + 1e-16f);
    const float4 b0 = *(const float4*)(b2 + cg*8);
    const float4 b4 = *(const float4*)(b2 + cg*8 + 4);
    float o[8];
    o[0]=a[0]*zi+b0.x; o[1]=a[1]*zi+b0.y; o[2]=a[2]*zi+b0.z; o[3]=a[3]*zi+b0.w;
    o[4]=a[4]*zi+b4.x; o[5]=a[5]*zi+b4.y; o[6]=a[6]*zi+b4.z; o[7]=a[7]*zi+b4.w;
    float mx = o[0];
    #pragma unroll
    for (int j = 1; j < 8; ++j) mx = fmaxf(mx, o[j]);
    mx = fmaxf(mx, __shfl_xor(mx, 1));
    float sum = 0.f;
    #pragma unroll
    for (int j = 0; j < 8; ++j) sum += expf(o[j] - mx);
    sum += __shfl_xor(sum, 1);
    if (es == 0){
        float ls = logf(sum);
        float* op = out + (size_t)n*16 + cg*8;
        *(float4*)op     = make_float4(o[0]-mx-ls, o[1]-mx-ls, o[2]-mx-ls, o[3]-mx-ls);
        *(float4*)(op+4) = make_float4(o[4]-mx-ls, o[5]-mx-ls, o[6]-mx-ls, o[7]-mx-ls);
    }
}

extern "C" void kernel_launch(void* const* d_in, const int* in_sizes, int n_in,
                              void* d_out, int out_size, void* d_ws, size_t ws_size,
                              hipStream_t stream)
{
    const float* x      = (const float*)d_in[0];
    const int*   ei     = (const int*)d_in[1];
    const float* W1     = (const float*)d_in[2];
    const float* a_src1 = (const float*)d_in[3];
    const float* a_dst1 = (const float*)d_in[4];
    const float* b1     = (const float*)d_in[5];
    const float* W2     = (const float*)d_in[6];
    const float* a_src2 = (const float*)d_in[7];
    const float* a_dst2 = (const float*)d_in[8];
    const float* b2     = (const float*)d_in[9];
    float* out = (float*)d_out;
    const int N  = in_sizes[0] / 128;
    const int E  = in_sizes[1] / 2;
    const int ET = E + N;

    char* ptr = (char*)d_ws;
    auto alloc = [&](size_t bytes)->char* {
        char* r = ptr; ptr += (bytes + 255) & ~(size_t)255; return r;
    };
    unsigned short* h1b    = (unsigned short*)alloc((size_t)N*64*2);
    unsigned short* h2b    = (unsigned short*)alloc((size_t)N*16*2);
    float*          s1     = (float*)alloc((size_t)N*4);
    float*          d1     = (float*)alloc((size_t)N*4);
    float*          s2     = (float*)alloc((size_t)N*4);
    float*          d2v    = (float*)alloc((size_t)N*4);
    int*            cnt    = (int*)alloc((size_t)N*4);
    int*            rowptr = (int*)alloc((size_t)(N+1)*4);
    unsigned*       rank32 = (unsigned*)alloc((size_t)((E+3)/4)*4);
    int2*           csrp   = (int2*)alloc((size_t)ET*8);
    int*            bsum   = (int*)alloc(4096);

    const int gET  = (ET + 255)/256;
    const int gE4  = ((E+3)/4 + 255)/256;
    const int nb1  = (N + 1023)/1024;
    const int nbN4 = (N + 3)/4;
    const int gG1  = (N + 63)/64;
    const int gRG1 = (gE4 > gG1) ? gE4 : gG1;

    // fused: rank chunk first (saturate RMW queue), GEMM tiles underneath
    hipMemsetAsync(cnt, 0, (size_t)N*4, stream);
    rg1<<<gRG1, 256, 0, stream>>>(x, W1, a_src1, a_dst1, h1b, s1, d1, N,
                                  ei, cnt, rank32, E);
    k_scan1<<<nb1, 256, 0, stream>>>(cnt, bsum, N);
    k_scan3<<<nb1, 256, 0, stream>>>(cnt, bsum, rowptr, N);

    // layer 1 score, then fused aggregate1+gemm2
    k_score<<<gET, 256, 0, stream>>>(ei, rank32, rowptr, s1, d1, csrp, E, ET);
    a1<<<nbN4, 256, 0, stream>>>(rowptr, csrp, h1b, b1, W2, a_src2, a_dst2,
                                 h2b, s2, d2v, N);

    // layer 2 aggregate (p2 inline, f32) + log_softmax
    a2<<<nbN4, 256, 0, stream>>>(rowptr, csrp, h2b, s2, d2v, b2, out, N);
}

// Round 21
// 407.481 us; speedup vs baseline: 1.0143x; 1.0143x over previous
//
#include <hip/hip_runtime.h>
#include <math.h>

#define NEG 0.2f

__device__ __forceinline__ float leaky(float x){ return x >= 0.f ? x : NEG*x; }

__device__ __forceinline__ unsigned short f2b(float f){
    unsigned u = __float_as_uint(f);
    unsigned r = u + 0x7fffu + ((u >> 16) & 1u);
    return (unsigned short)(r >> 16);
}

// ---------------- fused: rank chunk FIRST (real edges only), then g1 -------
// NOTE: atomic pass floor ~132us (memory-side RMW cap ~25G/s; ILP/padding/
// scope/role-split all measured null). Rank-first ordering hides the GEMM.
__global__ __launch_bounds__(256) void rg1(const float* __restrict__ x,
        const float* __restrict__ W1, const float* __restrict__ a_src,
        const float* __restrict__ a_dst, unsigned short* __restrict__ h1b,
        float* __restrict__ s1, float* __restrict__ d1, int N,
        const int* __restrict__ ei, int* __restrict__ cnt,
        unsigned* __restrict__ rank32, int E)
{
    __shared__ float wsh[128][64];
    const int tid = threadIdx.x;
    // ---- rank chunk (all blocks, FIRST; real edges only) ----
    int i0 = (blockIdx.x*256 + tid)*4;
    if (i0 < E){
        unsigned pk;
        if (i0 + 3 < E){
            int4 d4 = *(const int4*)(ei + E + i0);
            unsigned r0 = (unsigned)atomicAdd(&cnt[d4.x], 1);
            unsigned r1 = (unsigned)atomicAdd(&cnt[d4.y], 1);
            unsigned r2 = (unsigned)atomicAdd(&cnt[d4.z], 1);
            unsigned r3 = (unsigned)atomicAdd(&cnt[d4.w], 1);
            pk = (r0 & 255u) | ((r1 & 255u) << 8) | ((r2 & 255u) << 16) | ((r3 & 255u) << 24);
        } else {
            pk = 0u;
            #pragma unroll
            for (int u = 0; u < 4; ++u){
                int i = i0 + u;
                if (i < E){
                    int dst = ei[E + i];
                    pk |= ((unsigned)atomicAdd(&cnt[dst], 1) & 255u) << (u*8);
                }
            }
        }
        rank32[i0 >> 2] = pk;
    }
    // ---- GEMM tile (blocks < gG1) ----
    const int gG1 = (N + 63) >> 6;
    if ((int)blockIdx.x >= gG1) return;
    const int rowbase = blockIdx.x * 64;
    #pragma unroll
    for (int i = 0; i < 8; ++i){
        int g = tid + i*256;
        ((float4*)&wsh[0][0])[g] = ((const float4*)W1)[g];
    }
    __syncthreads();
    const int tx = tid & 15, ty = tid >> 4;
    const int r0 = rowbase + ty*4;
    const float4* xr0 = (const float4*)(x + (size_t)min(r0+0, N-1)*128);
    const float4* xr1 = (const float4*)(x + (size_t)min(r0+1, N-1)*128);
    const float4* xr2 = (const float4*)(x + (size_t)min(r0+2, N-1)*128);
    const float4* xr3 = (const float4*)(x + (size_t)min(r0+3, N-1)*128);
    float acc[4][4];
    #pragma unroll
    for (int j=0;j<4;++j){
        #pragma unroll
        for (int c=0;c<4;++c) acc[j][c]=0.f;
    }
    #pragma unroll 4
    for (int k4 = 0; k4 < 32; ++k4){
        float4 xv[4], wv[4];
        xv[0] = xr0[k4]; xv[1] = xr1[k4]; xv[2] = xr2[k4]; xv[3] = xr3[k4];
        #pragma unroll
        for (int i=0;i<4;++i) wv[i] = *(const float4*)&wsh[k4*4+i][tx*4];
        #pragma unroll
        for (int j=0;j<4;++j){
            float x0=xv[j].x, x1=xv[j].y, x2=xv[j].z, x3=xv[j].w;
            acc[j][0]=fmaf(x0,wv[0].x,acc[j][0]); acc[j][1]=fmaf(x0,wv[0].y,acc[j][1]);
            acc[j][2]=fmaf(x0,wv[0].z,acc[j][2]); acc[j][3]=fmaf(x0,wv[0].w,acc[j][3]);
            acc[j][0]=fmaf(x1,wv[1].x,acc[j][0]); acc[j][1]=fmaf(x1,wv[1].y,acc[j][1]);
            acc[j][2]=fmaf(x1,wv[1].z,acc[j][2]); acc[j][3]=fmaf(x1,wv[1].w,acc[j][3]);
            acc[j][0]=fmaf(x2,wv[2].x,acc[j][0]); acc[j][1]=fmaf(x2,wv[2].y,acc[j][1]);
            acc[j][2]=fmaf(x2,wv[2].z,acc[j][2]); acc[j][3]=fmaf(x2,wv[2].w,acc[j][3]);
            acc[j][0]=fmaf(x3,wv[3].x,acc[j][0]); acc[j][1]=fmaf(x3,wv[3].y,acc[j][1]);
            acc[j][2]=fmaf(x3,wv[3].z,acc[j][2]); acc[j][3]=fmaf(x3,wv[3].w,acc[j][3]);
        }
    }
    const float4 asv = *(const float4*)&a_src[tx*4];
    const float4 adv = *(const float4*)&a_dst[tx*4];
    #pragma unroll
    for (int j=0;j<4;++j){
        int r = rowbase + ty*4 + j;
        float sv = acc[j][0]*asv.x + acc[j][1]*asv.y + acc[j][2]*asv.z + acc[j][3]*asv.w;
        float dv = acc[j][0]*adv.x + acc[j][1]*adv.y + acc[j][2]*adv.z + acc[j][3]*adv.w;
        #pragma unroll
        for (int dd=8; dd>0; dd>>=1){ sv += __shfl_xor(sv, dd, 16); dv += __shfl_xor(dv, dd, 16); }
        if (r < N){
            uint2 pk;
            pk.x = (unsigned)f2b(acc[j][0]) | ((unsigned)f2b(acc[j][1]) << 16);
            pk.y = (unsigned)f2b(acc[j][2]) | ((unsigned)f2b(acc[j][3]) << 16);
            *(uint2*)&h1b[(size_t)r*64 + tx*4] = pk;
            if (tx == 0){ s1[r] = sv; d1[r] = dv; }
        }
    }
}

__global__ void k_scan1(const int* __restrict__ cnt, int* __restrict__ bsum, int n){
    __shared__ int sh[256];
    int b = blockIdx.x, tid = threadIdx.x;
    int start = b*1024, s = 0;
    for (int i = tid; i < 1024; i += 256){ int idx = start+i; s += (idx<n)?cnt[idx]:0; }
    sh[tid]=s; __syncthreads();
    for (int d=128; d>0; d>>=1){ if (tid<d) sh[tid]+=sh[tid+d]; __syncthreads(); }
    if (tid==0) bsum[b]=sh[0];
}
// scan3: rowptr from cnt_real + 1 slot/node (trailing self-loop slot)
__global__ void k_scan3(const int* __restrict__ cnt, const int* __restrict__ bsum,
                        int* __restrict__ rowptr, int n){
    __shared__ int sh[256];
    __shared__ int basesh;
    int b = blockIdx.x, tid = threadIdx.x;
    int pb = 0;
    for (int i = tid; i < b; i += 256) pb += bsum[i];
    sh[tid] = pb; __syncthreads();
    for (int d=128; d>0; d>>=1){ if (tid<d) sh[tid]+=sh[tid+d]; __syncthreads(); }
    if (tid==0) basesh = sh[0] + b*1024;   // +1 slot per preceding node
    __syncthreads();
    int base = basesh;
    __syncthreads();
    int i0 = b*1024 + tid*4;
    int v[4]; int local=0;
    #pragma unroll
    for (int k=0;k<4;k++){ int idx=i0+k; v[k]=(idx<n)?(cnt[idx]+1):0; local+=v[k]; }
    sh[tid]=local; __syncthreads();
    for (int d=1; d<256; d<<=1){
        int t = (tid>=d)? sh[tid-d] : 0;
        __syncthreads();
        sh[tid] += t;
        __syncthreads();
    }
    int off = base + sh[tid] - local;
    #pragma unroll
    for (int k=0;k<4;k++){
        int idx = i0+k;
        if (idx < n){
            rowptr[idx]=off; off += v[k];
            if (idx==n-1) rowptr[n]=off;
        }
    }
}

// ---------------- score: {src, p1} int2; self-loop -> last slot of row -----
__global__ void k_score(const int* __restrict__ ei, const unsigned* __restrict__ rank32,
                        const int* __restrict__ rowptr,
                        const float* __restrict__ s, const float* __restrict__ d,
                        int2* __restrict__ csrp, int E, int ET){
    int i = blockIdx.x*256 + threadIdx.x;
    if (i >= ET) return;
    if (i < E){
        int src = ei[i];
        int dst = ei[E + i];
        int lr = (int)((rank32[i >> 2] >> ((i & 3)*8)) & 255u);
        float pv = expf(leaky(s[src] + d[dst]));
        csrp[rowptr[dst] + lr] = make_int2(src, __float_as_int(pv));
    } else {
        int nn = i - E;
        float pv = expf(leaky(s[nn] + d[nn]));
        csrp[rowptr[nn+1] - 1] = make_int2(nn, __float_as_int(pv));
    }
}

// ---------------- a1 fused with g2: aggregate layer 1 -> h2b, s2, d2 -------
// NOTE: no shfl-broadcast of loaded data (unsound on this target — r1/2/19).
// 2x manual unroll: two csrp loads + two row-gathers in flight per lane;
// tail handled by zero-weight duplicate (fmaf(0,x,a)==a exactly).
__global__ __launch_bounds__(256) void a1(const int* __restrict__ rowptr,
        const int2* __restrict__ csrp, const unsigned short* __restrict__ h1b,
        const float* __restrict__ b1, const float* __restrict__ W2,
        const float* __restrict__ as2, const float* __restrict__ ad2,
        unsigned short* __restrict__ h2b, float* __restrict__ s2,
        float* __restrict__ d2, int N)
{
    int wid = threadIdx.x>>6, lane = threadIdx.x&63;
    int es = lane >> 3, cg = lane & 7;
    float2 w2r[8];
    #pragma unroll
    for (int j = 0; j < 8; ++j)
        w2r[j] = *(const float2*)&W2[(cg*8 + j)*16 + es*2];
    const float2 asv = *(const float2*)&as2[es*2];
    const float2 adv = *(const float2*)&ad2[es*2];
    int n = blockIdx.x*4 + wid;
    if (n >= N) return;
    int base = rowptr[n], end = rowptr[n+1];
    float a0=0.f,a1v=0.f,a2v=0.f,a3=0.f,a4=0.f,a5=0.f,a6=0.f,a7=0.f;
    float z = 0.f;
    for (int k = base + es; k < end; k += 16){
        int k2 = k + 8;
        bool v2 = (k2 < end);
        int2 cp1 = csrp[k];
        int2 cp2 = csrp[v2 ? k2 : k];
        float pv1 = __int_as_float(cp1.y);
        float pv2 = v2 ? __int_as_float(cp2.y) : 0.f;
        const uint4* g1p = (const uint4*)(h1b + (size_t)cp1.x*64 + cg*8);
        const uint4* g2p = (const uint4*)(h1b + (size_t)cp2.x*64 + cg*8);
        uint4 hv1 = *g1p;
        uint4 hv2 = *g2p;
        z += pv1;
        a0 = fmaf(pv1, __uint_as_float(hv1.x << 16),          a0);
        a1v= fmaf(pv1, __uint_as_float(hv1.x & 0xffff0000u),  a1v);
        a2v= fmaf(pv1, __uint_as_float(hv1.y << 16),          a2v);
        a3 = fmaf(pv1, __uint_as_float(hv1.y & 0xffff0000u),  a3);
        a4 = fmaf(pv1, __uint_as_float(hv1.z << 16),          a4);
        a5 = fmaf(pv1, __uint_as_float(hv1.z & 0xffff0000u),  a5);
        a6 = fmaf(pv1, __uint_as_float(hv1.w << 16),          a6);
        a7 = fmaf(pv1, __uint_as_float(hv1.w & 0xffff0000u),  a7);
        z += pv2;
        a0 = fmaf(pv2, __uint_as_float(hv2.x << 16),          a0);
        a1v= fmaf(pv2, __uint_as_float(hv2.x & 0xffff0000u),  a1v);
        a2v= fmaf(pv2, __uint_as_float(hv2.y << 16),          a2v);
        a3 = fmaf(pv2, __uint_as_float(hv2.y & 0xffff0000u),  a3);
        a4 = fmaf(pv2, __uint_as_float(hv2.z << 16),          a4);
        a5 = fmaf(pv2, __uint_as_float(hv2.z & 0xffff0000u),  a5);
        a6 = fmaf(pv2, __uint_as_float(hv2.w << 16),          a6);
        a7 = fmaf(pv2, __uint_as_float(hv2.w & 0xffff0000u),  a7);
    }
    #pragma unroll
    for (int m = 8; m <= 32; m <<= 1){
        a0 += __shfl_xor(a0, m); a1v += __shfl_xor(a1v, m);
        a2v += __shfl_xor(a2v, m); a3 += __shfl_xor(a3, m);
        a4 += __shfl_xor(a4, m); a5 += __shfl_xor(a5, m);
        a6 += __shfl_xor(a6, m); a7 += __shfl_xor(a7, m);
        z  += __shfl_xor(z, m);
    }
    float zi = 1.f/(z + 1e-16f);
    const float4 b0 = *(const float4*)(b1 + cg*8);
    const float4 b4 = *(const float4*)(b1 + cg*8 + 4);
    float o[8];
    o[0]=fmaxf(a0*zi + b0.x, 0.f); o[1]=fmaxf(a1v*zi + b0.y, 0.f);
    o[2]=fmaxf(a2v*zi + b0.z, 0.f); o[3]=fmaxf(a3*zi + b0.w, 0.f);
    o[4]=fmaxf(a4*zi + b4.x, 0.f); o[5]=fmaxf(a5*zi + b4.y, 0.f);
    o[6]=fmaxf(a6*zi + b4.z, 0.f); o[7]=fmaxf(a7*zi + b4.w, 0.f);
    float pc0 = 0.f, pc1 = 0.f;
    #pragma unroll
    for (int j = 0; j < 8; ++j){
        pc0 = fmaf(o[j], w2r[j].x, pc0);
        pc1 = fmaf(o[j], w2r[j].y, pc1);
    }
    #pragma unroll
    for (int m = 1; m <= 4; m <<= 1){ pc0 += __shfl_xor(pc0, m); pc1 += __shfl_xor(pc1, m); }
    float sp = pc0*asv.x + pc1*asv.y;
    float dp = pc0*adv.x + pc1*adv.y;
    #pragma unroll
    for (int m = 8; m <= 32; m <<= 1){ sp += __shfl_xor(sp, m); dp += __shfl_xor(dp, m); }
    if (cg == 0){
        unsigned pk = (unsigned)f2b(pc0) | ((unsigned)f2b(pc1) << 16);
        *(unsigned*)&h2b[(size_t)n*16 + es*2] = pk;
        if (es == 0){ s2[n] = sp; d2[n] = dp; }
    }
}

// ---------------- a2: aggregate layer 2 (p2 inline, f32) + log_softmax -----
__global__ __launch_bounds__(256) void a2(const int* __restrict__ rowptr,
        const int2* __restrict__ csrp, const unsigned short* __restrict__ h2b,
        const float* __restrict__ s2, const float* __restrict__ d2,
        const float* __restrict__ b2, float* __restrict__ out, int N)
{
    int wid = threadIdx.x>>6, lane = threadIdx.x&63;
    int n = blockIdx.x*4 + wid;
    if (n >= N) return;
    int base = rowptr[n], end = rowptr[n+1];
    int es = lane >> 1, cg = lane & 1;
    float dn = d2[n];
    float a[8] = {0.f,0.f,0.f,0.f,0.f,0.f,0.f,0.f};
    float z = 0.f;
    for (int k = base + es; k < end; k += 32){
        int2 cp = csrp[k];
        float pv = expf(leaky(s2[cp.x] + dn));
        z += pv;
        uint4 hv = *(const uint4*)(h2b + (size_t)cp.x*16 + cg*8);
        a[0] = fmaf(pv, __uint_as_float(hv.x << 16),          a[0]);
        a[1] = fmaf(pv, __uint_as_float(hv.x & 0xffff0000u),  a[1]);
        a[2] = fmaf(pv, __uint_as_float(hv.y << 16),          a[2]);
        a[3] = fmaf(pv, __uint_as_float(hv.y & 0xffff0000u),  a[3]);
        a[4] = fmaf(pv, __uint_as_float(hv.z << 16),          a[4]);
        a[5] = fmaf(pv, __uint_as_float(hv.z & 0xffff0000u),  a[5]);
        a[6] = fmaf(pv, __uint_as_float(hv.w << 16),          a[6]);
        a[7] = fmaf(pv, __uint_as_float(hv.w & 0xffff0000u),  a[7]);
    }
    #pragma unroll
    for (int m = 2; m <= 32; m <<= 1){
        #pragma unroll
        for (int j = 0; j < 8; ++j) a[j] += __shfl_xor(a[j], m);
        z += __shfl_xor(z, m);
    }
    float zi = 1.f/(z + 1e-16f);
    const float4 b0 = *(const float4*)(b2 + cg*8);
    const float4 b4 = *(const float4*)(b2 + cg*8 + 4);
    float o[8];
    o[0]=a[0]*zi+b0.x; o[1]=a[1]*zi+b0.y; o[2]=a[2]*zi+b0.z; o[3]=a[3]*zi+b0.w;
    o[4]=a[4]*zi+b4.x; o[5]=a[5]*zi+b4.y; o[6]=a[6]*zi+b4.z; o[7]=a[7]*zi+b4.w;
    float mx = o[0];
    #pragma unroll
    for (int j = 1; j < 8; ++j) mx = fmaxf(mx, o[j]);
    mx = fmaxf(mx, __shfl_xor(mx, 1));
    float sum = 0.f;
    #pragma unroll
    for (int j = 0; j < 8; ++j) sum += expf(o[j] - mx);
    sum += __shfl_xor(sum, 1);
    if (es == 0){
        float ls = logf(sum);
        float* op = out + (size_t)n*16 + cg*8;
        *(float4*)op     = make_float4(o[0]-mx-ls, o[1]-mx-ls, o[2]-mx-ls, o[3]-mx-ls);
        *(float4*)(op+4) = make_float4(o[4]-mx-ls, o[5]-mx-ls, o[6]-mx-ls, o[7]-mx-ls);
    }
}

extern "C" void kernel_launch(void* const* d_in, const int* in_sizes, int n_in,
                              void* d_out, int out_size, void* d_ws, size_t ws_size,
                              hipStream_t stream)
{
    const float* x      = (const float*)d_in[0];
    const int*   ei     = (const int*)d_in[1];
    const float* W1     = (const float*)d_in[2];
    const float* a_src1 = (const float*)d_in[3];
    const float* a_dst1 = (const float*)d_in[4];
    const float* b1     = (const float*)d_in[5];
    const float* W2     = (const float*)d_in[6];
    const float* a_src2 = (const float*)d_in[7];
    const float* a_dst2 = (const float*)d_in[8];
    const float* b2     = (const float*)d_in[9];
    float* out = (float*)d_out;
    const int N  = in_sizes[0] / 128;
    const int E  = in_sizes[1] / 2;
    const int ET = E + N;

    char* ptr = (char*)d_ws;
    auto alloc = [&](size_t bytes)->char* {
        char* r = ptr; ptr += (bytes + 255) & ~(size_t)255; return r;
    };
    unsigned short* h1b    = (unsigned short*)alloc((size_t)N*64*2);
    unsigned short* h2b    = (unsigned short*)alloc((size_t)N*16*2);
    float*          s1     = (float*)alloc((size_t)N*4);
    float*          d1     = (float*)alloc((size_t)N*4);
    float*          s2     = (float*)alloc((size_t)N*4);
    float*          d2v    = (float*)alloc((size_t)N*4);
    int*            cnt    = (int*)alloc((size_t)N*4);
    int*            rowptr = (int*)alloc((size_t)(N+1)*4);
    unsigned*       rank32 = (unsigned*)alloc((size_t)((E+3)/4)*4);
    int2*           csrp   = (int2*)alloc((size_t)ET*8);
    int*            bsum   = (int*)alloc(4096);

    const int gET  = (ET + 255)/256;
    const int gE4  = ((E+3)/4 + 255)/256;
    const int nb1  = (N + 1023)/1024;
    const int nbN4 = (N + 3)/4;
    const int gG1  = (N + 63)/64;
    const int gRG1 = (gE4 > gG1) ? gE4 : gG1;

    // fused: rank chunk first (saturate RMW queue), GEMM tiles underneath
    hipMemsetAsync(cnt, 0, (size_t)N*4, stream);
    rg1<<<gRG1, 256, 0, stream>>>(x, W1, a_src1, a_dst1, h1b, s1, d1, N,
                                  ei, cnt, rank32, E);
    k_scan1<<<nb1, 256, 0, stream>>>(cnt, bsum, N);
    k_scan3<<<nb1, 256, 0, stream>>>(cnt, bsum, rowptr, N);

    // layer 1 score, then fused aggregate1+gemm2
    k_score<<<gET, 256, 0, stream>>>(ei, rank32, rowptr, s1, d1, csrp, E, ET);
    a1<<<nbN4, 256, 0, stream>>>(rowptr, csrp, h1b, b1, W2, a_src2, a_dst2,
                                 h2b, s2, d2v, N);

    // layer 2 aggregate (p2 inline, f32) + log_softmax
    a2<<<nbN4, 256, 0, stream>>>(rowptr, csrp, h2b, s2, d2v, b2, out, N);
}